// Round 5
// baseline (542.472 us; speedup 1.0000x reference)
//
#include <hip/hip_runtime.h>

#define NN 50000
#define NE 400000
#define DD 512
#define NB 196  // ceil(NN/256)

typedef unsigned short u16;
typedef float f32x4 __attribute__((ext_vector_type(4)));
typedef __bf16 bf16x8 __attribute__((ext_vector_type(8)));

__device__ __forceinline__ u16 f2bf(float f) {
  unsigned u = __builtin_bit_cast(unsigned, f);
  unsigned r = (u + 0x7FFFu + ((u >> 16) & 1u)) >> 16;
  return (u16)r;
}
__device__ __forceinline__ float bf_lo(unsigned v) {
  return __builtin_bit_cast(float, v << 16);
}
__device__ __forceinline__ float bf_hi(unsigned v) {
  return __builtin_bit_cast(float, v & 0xffff0000u);
}

__device__ __forceinline__ void gload16(const void* g, void* l) {
  __builtin_amdgcn_global_load_lds(
      (const __attribute__((address_space(1))) unsigned int*)g,
      (__attribute__((address_space(3))) unsigned int*)l, 16, 0, 0);
}

// ---------- edge dtype detect + normalize ----------
__global__ void k_detect(const long long* __restrict__ p, int* __restrict__ vio) {
  bool bad = false;
  for (int i = blockIdx.x * blockDim.x + threadIdx.x; i < NE; i += blockDim.x * gridDim.x) {
    long long v = p[i];
    bad |= (v < 0 || v >= NN);
  }
  unsigned long long m = __ballot(bad);
  if (m != 0ull && (threadIdx.x & 63) == 0) atomicOr(vio, 1);
}

__global__ void k_norm(const void* __restrict__ ep, const int* __restrict__ vio,
                       int* __restrict__ src, int* __restrict__ dst) {
  bool is64 = (*vio == 0);
  for (int e = blockIdx.x * blockDim.x + threadIdx.x; e < NE; e += blockDim.x * gridDim.x) {
    if (is64) {
      const long long* p = (const long long*)ep;
      src[e] = (int)p[e];
      dst[e] = (int)p[NE + e];
    } else {
      const int* p = (const int*)ep;
      src[e] = p[e];
      dst[e] = p[NE + e];
    }
  }
}

// ---------- degree / scan / CSR ----------
__global__ void k_count(const int* __restrict__ dst, int* __restrict__ deg) {
  int e = blockIdx.x * 256 + threadIdx.x;
  if (e < NE) atomicAdd(&deg[dst[e]], 1);
}

__global__ void k_scan1(const int* __restrict__ deg, int* __restrict__ offs,
                        int* __restrict__ bsums) {
  __shared__ int sm[256];
  int t = threadIdx.x, i = blockIdx.x * 256 + t;
  int v = (i < NN) ? deg[i] : 0;
  sm[t] = v;
  __syncthreads();
  int x = v;
  for (int d = 1; d < 256; d <<= 1) {
    int y = (t >= d) ? sm[t - d] : 0;
    __syncthreads();
    x += y;
    sm[t] = x;
    __syncthreads();
  }
  if (i < NN) offs[i + 1] = x;
  if (t == 255) bsums[blockIdx.x] = x;
}

__global__ void k_scan2(const int* __restrict__ bsums, int* __restrict__ boffs) {
  __shared__ int sm[256];
  int t = threadIdx.x;
  int v = (t < NB) ? bsums[t] : 0;
  sm[t] = v;
  __syncthreads();
  int x = v;
  for (int d = 1; d < 256; d <<= 1) {
    int y = (t >= d) ? sm[t - d] : 0;
    __syncthreads();
    x += y;
    sm[t] = x;
    __syncthreads();
  }
  if (t < NB) boffs[t] = x - v;  // exclusive
}

__global__ void k_scan3(int* __restrict__ offs, const int* __restrict__ boffs,
                        const int* __restrict__ deg, float* __restrict__ invd) {
  int i = blockIdx.x * 256 + threadIdx.x;
  if (i == 0) offs[0] = 0;
  if (i < NN) {
    offs[i + 1] += boffs[i >> 8];
    int dg = deg[i];
    if (dg < 1) dg = 1;
    invd[i] = 1.0f / (float)dg;
  }
}

__global__ void k_fill(const int* __restrict__ src, const int* __restrict__ dst,
                       const int* __restrict__ offs, int* __restrict__ cursor,
                       int* __restrict__ csr) {
  int e = blockIdx.x * 256 + threadIdx.x;
  if (e < NE) {
    int d = dst[e];
    int p = atomicAdd(&cursor[d], 1);
    csr[offs[d] + p] = src[e];
  }
}

// ---------- weight transpose + bf16 convert: Wt[n][k] = W[k][n] ----------
__global__ void k_wt(const float* __restrict__ W, u16* __restrict__ Wt) {
  __shared__ float t[32][33];
  int tx = threadIdx.x & 31, ty = threadIdx.x >> 5;  // 32x8
  int bx = blockIdx.x, by = blockIdx.y;
#pragma unroll
  for (int i = 0; i < 32; i += 8)
    t[ty + i][tx] = W[(size_t)(bx * 32 + ty + i) * DD + by * 32 + tx];
  __syncthreads();
#pragma unroll
  for (int i = 0; i < 32; i += 8)
    Wt[(size_t)(by * 32 + ty + i) * DD + bx * 32 + tx] = f2bf(t[tx][ty + i]);
}

// ---------- x f32 -> bf16 ----------
__global__ void k_cvt(const float* __restrict__ x, u16* __restrict__ xb) {
  size_t i = (size_t)(blockIdx.x * 256 + threadIdx.x) * 8;
  float4 a = *(const float4*)(x + i);
  float4 b = *(const float4*)(x + i + 4);
  uint4 o;
  o.x = (unsigned)f2bf(a.x) | ((unsigned)f2bf(a.y) << 16);
  o.y = (unsigned)f2bf(a.z) | ((unsigned)f2bf(a.w) << 16);
  o.z = (unsigned)f2bf(b.x) | ((unsigned)f2bf(b.y) << 16);
  o.w = (unsigned)f2bf(b.z) | ((unsigned)f2bf(b.w) << 16);
  *(uint4*)(xb + i) = o;
}

// ---------- aggregation: one wave per node, 4-deep load pipeline ----------
__global__ __launch_bounds__(256) void k_agg(const u16* __restrict__ xb,
                                             const int* __restrict__ offs,
                                             const int* __restrict__ csr,
                                             const float* __restrict__ invd,
                                             u16* __restrict__ agg) {
  int node = blockIdx.x * 4 + (threadIdx.x >> 6);
  int lane = threadIdx.x & 63;
  if (node >= NN) return;
  int s = offs[node], e = offs[node + 1];
  float a0 = 0, a1 = 0, a2 = 0, a3 = 0, a4 = 0, a5 = 0, a6 = 0, a7 = 0;
  int j = s;
  for (; j + 4 <= e; j += 4) {
    int u0 = csr[j], u1 = csr[j + 1], u2 = csr[j + 2], u3 = csr[j + 3];
    uint4 v0 = *(const uint4*)(xb + (size_t)u0 * DD + lane * 8);
    uint4 v1 = *(const uint4*)(xb + (size_t)u1 * DD + lane * 8);
    uint4 v2 = *(const uint4*)(xb + (size_t)u2 * DD + lane * 8);
    uint4 v3 = *(const uint4*)(xb + (size_t)u3 * DD + lane * 8);
    a0 += bf_lo(v0.x); a1 += bf_hi(v0.x); a2 += bf_lo(v0.y); a3 += bf_hi(v0.y);
    a4 += bf_lo(v0.z); a5 += bf_hi(v0.z); a6 += bf_lo(v0.w); a7 += bf_hi(v0.w);
    a0 += bf_lo(v1.x); a1 += bf_hi(v1.x); a2 += bf_lo(v1.y); a3 += bf_hi(v1.y);
    a4 += bf_lo(v1.z); a5 += bf_hi(v1.z); a6 += bf_lo(v1.w); a7 += bf_hi(v1.w);
    a0 += bf_lo(v2.x); a1 += bf_hi(v2.x); a2 += bf_lo(v2.y); a3 += bf_hi(v2.y);
    a4 += bf_lo(v2.z); a5 += bf_hi(v2.z); a6 += bf_lo(v2.w); a7 += bf_hi(v2.w);
    a0 += bf_lo(v3.x); a1 += bf_hi(v3.x); a2 += bf_lo(v3.y); a3 += bf_hi(v3.y);
    a4 += bf_lo(v3.z); a5 += bf_hi(v3.z); a6 += bf_lo(v3.w); a7 += bf_hi(v3.w);
  }
  for (; j < e; ++j) {
    int u = csr[j];
    uint4 v = *(const uint4*)(xb + (size_t)u * DD + lane * 8);
    a0 += bf_lo(v.x); a1 += bf_hi(v.x); a2 += bf_lo(v.y); a3 += bf_hi(v.y);
    a4 += bf_lo(v.z); a5 += bf_hi(v.z); a6 += bf_lo(v.w); a7 += bf_hi(v.w);
  }
  float sc = invd[node];
  uint4 o;
  o.x = (unsigned)f2bf(a0 * sc) | ((unsigned)f2bf(a1 * sc) << 16);
  o.y = (unsigned)f2bf(a2 * sc) | ((unsigned)f2bf(a3 * sc) << 16);
  o.z = (unsigned)f2bf(a4 * sc) | ((unsigned)f2bf(a5 * sc) << 16);
  o.w = (unsigned)f2bf(a6 * sc) | ((unsigned)f2bf(a7 * sc) << 16);
  *(uint4*)(agg + (size_t)node * DD + lane * 8) = o;
}

// ---------- fused GEMM: C = relu?(Agg@Wl + X@Wr + b) ----------
// BM=128, BN=128, BK=32, 4 waves (2x2). Triple-buffered LDS (48KB -> 3
// blocks/CU), ONE barrier per K-step: vmcnt(4) confirms own tile-t loads;
// s_barrier => ALL waves' tile-t writes landed (R4-validated pattern);
// stage(t+2) into buf (t-1)%3 (freed: every wave finished compute(t-1)
// before this barrier); compute(t). vmcnt never 0 until the peeled tail.
// Granule-XOR swizzle g^((row>>1)&3) on 64B rows: 2-way banks = free.
__global__ __launch_bounds__(256) void k_gemm(const u16* __restrict__ Aagg,
                                              const u16* __restrict__ Ax,
                                              const u16* __restrict__ Wlt,
                                              const u16* __restrict__ Wrt,
                                              const float* __restrict__ bias,
                                              u16* __restrict__ ybf,
                                              float* __restrict__ yf,
                                              int do_relu) {
  // A bufs: [0,12288) = 3 x 4096 u16; B bufs: [12288,24576). 48KB total.
  __shared__ u16 sh[24576] __attribute__((aligned(16)));

  int tid = threadIdx.x;
  int w = tid >> 6, lane = tid & 63;
  int wr = w >> 1, wc = w & 1;
  int lr = lane & 15;
  int hi = lane >> 4;  // 0..3 = k-granule of the MFMA fragment

  // XCD-bijective decode: same rowTile's 4 colTiles land consecutively on one XCD
  int lin = blockIdx.x;
  int xcd = lin & 7;
  int t = lin >> 3;
  int colT = t & 3;
  int rowT = (t >> 2) * 8 + xcd;  // 0..391
  int blockRow = rowT * 128;
  int nbase = colT * 128;

  // staging: lane l of chunk c writes LDS row r=c*16+l/4, granule gd=l&3
  // (linear dest); source granule pre-swizzled: gs = gd ^ ((r>>1)&3)
  int rsub = lane >> 2;   // 0..15
  int gd = lane & 3;

  f32x4 acc[4][4];
#pragma unroll
  for (int m = 0; m < 4; ++m)
#pragma unroll
    for (int n = 0; n < 4; ++n) acc[m][n] = (f32x4){0.f, 0.f, 0.f, 0.f};

  // stage K-tile kt (0..31) into buffer b: 2 A + 2 B gload16 per thread
  auto stage = [&](int kt, int b) {
    const u16* Ap = (kt < 16) ? Aagg : Ax;
    const u16* Bp = (kt < 16) ? Wlt : Wrt;
    int kb = (kt & 15) << 5;
    u16* Ad = sh + b * 4096;
    u16* Bd = sh + 12288 + b * 4096;
#pragma unroll
    for (int i = 0; i < 2; ++i) {
      int c = (w << 1) + i;         // chunk 0..7 (16 rows each)
      int rloc = c * 16 + rsub;     // LDS-local row 0..127
      int gs = (gd ^ ((rloc >> 1) & 3)) << 3;  // swizzled source granule (elems)
      int rA = blockRow + rloc;
      if (rA > NN - 1) rA = NN - 1;
      int rB = nbase + rloc;
      gload16(Ap + (size_t)rA * DD + kb + gs, Ad + c * 512);
      gload16(Bp + (size_t)rB * DD + kb + gs, Bd + c * 512);
    }
  };

  auto compute = [&](int b) {
    const u16* As = sh + b * 4096;
    const u16* Bs = sh + 12288 + b * 4096;
    bf16x8 af[4], bfr[4];
#pragma unroll
    for (int m = 0; m < 4; ++m) {
      int r = wr * 64 + m * 16 + lr;
      af[m] = *(const bf16x8*)(As + r * 32 + ((hi ^ ((r >> 1) & 3)) << 3));
    }
#pragma unroll
    for (int n = 0; n < 4; ++n) {
      int r = wc * 64 + n * 16 + lr;
      bfr[n] = *(const bf16x8*)(Bs + r * 32 + ((hi ^ ((r >> 1) & 3)) << 3));
    }
    __builtin_amdgcn_s_setprio(1);
#pragma unroll
    for (int m = 0; m < 4; ++m)
#pragma unroll
      for (int n = 0; n < 4; ++n)
        acc[m][n] = __builtin_amdgcn_mfma_f32_16x16x32_bf16(af[m], bfr[n], acc[m][n], 0, 0, 0);
    __builtin_amdgcn_s_setprio(0);
  };

  stage(0, 0);
  stage(1, 1);  // 8 loads outstanding

  int rb = 0, sb = 2;
  for (int kt = 0; kt < 30; ++kt) {
    // own tile-kt loads done (<=4 newer remain: tile kt+1)
    asm volatile("s_waitcnt vmcnt(4)" ::: "memory");
    __builtin_amdgcn_s_barrier();  // => ALL waves' tile-kt writes landed
    stage(kt + 2, sb);             // buf freed by compute(kt-1) pre-barrier
    compute(rb);
    rb = (rb == 2) ? 0 : rb + 1;
    sb = (sb == 2) ? 0 : sb + 1;
  }
  // kt=30: tile 31 still in flight
  asm volatile("s_waitcnt vmcnt(4)" ::: "memory");
  __builtin_amdgcn_s_barrier();
  compute(rb);
  rb = (rb == 2) ? 0 : rb + 1;
  // kt=31: final drain
  asm volatile("s_waitcnt vmcnt(0)" ::: "memory");
  __builtin_amdgcn_s_barrier();
  compute(rb);

  if (yf) {
    // f32 output (final layer): 64B-contiguous per 16 lanes -> sector-aligned
#pragma unroll
    for (int n = 0; n < 4; ++n) {
      int col = nbase + wc * 64 + n * 16 + lr;
      float bv = bias[col];
#pragma unroll
      for (int m = 0; m < 4; ++m) {
        f32x4 v = acc[m][n];
#pragma unroll
        for (int r = 0; r < 4; ++r) {
          int row = blockRow + wr * 64 + m * 16 + hi * 4 + r;
          if (row < NN) {
            float y = v[r] + bv;
            if (do_relu) y = fmaxf(y, 0.f);
            yf[(size_t)row * DD + col] = y;
          }
        }
      }
    }
  } else {
    // bf16 output: stage C tile (128x128 u16 = 32KB in sh[0..16384)) then coalesced writes
    __syncthreads();  // all compute reads done before reusing sh
#pragma unroll
    for (int n = 0; n < 4; ++n) {
      int col = nbase + wc * 64 + n * 16 + lr;
      float bv = bias[col];
      int g = wc * 8 + n * 2 + (lr >> 3);  // col granule 0..15
#pragma unroll
      for (int m = 0; m < 4; ++m) {
        f32x4 v = acc[m][n];
#pragma unroll
        for (int r = 0; r < 4; ++r) {
          int rl = wr * 64 + m * 16 + hi * 4 + r;
          float y = v[r] + bv;
          if (do_relu) y = fmaxf(y, 0.f);
          sh[rl * 128 + ((g ^ (rl & 15)) << 3) + (lr & 7)] = f2bf(y);
        }
      }
    }
    __syncthreads();
#pragma unroll
    for (int p = 0; p < 8; ++p) {
      int rl = p * 16 + (tid >> 4);
      int gg = tid & 15;
      int grow = blockRow + rl;
      if (grow < NN) {
        uint4 vv = *(const uint4*)(sh + rl * 128 + ((gg ^ (rl & 15)) << 3));
        *(uint4*)(ybf + (size_t)grow * DD + nbase + gg * 8) = vv;
      }
    }
  }
}

extern "C" void kernel_launch(void* const* d_in, const int* in_sizes, int n_in,
                              void* d_out, int out_size, void* d_ws, size_t ws_size,
                              hipStream_t stream) {
  const float* x_in = (const float*)d_in[0];
  const void* eidx = d_in[1];
  const float* Wl[3] = {(const float*)d_in[2], (const float*)d_in[5], (const float*)d_in[8]};
  const float* bl[3] = {(const float*)d_in[3], (const float*)d_in[6], (const float*)d_in[9]};
  const float* Wr[3] = {(const float*)d_in[4], (const float*)d_in[7], (const float*)d_in[10]};

  // workspace layout
  char* w = (char*)d_ws;
  auto alloc = [&](size_t bytes) {
    char* p = w;
    w += (bytes + 255) & ~(size_t)255;
    return p;
  };
  int* vio = (int*)alloc(4);
  int* deg = (int*)alloc((size_t)NN * 4);
  int* cursor = (int*)alloc((size_t)NN * 4);
  int* offs = (int*)alloc((size_t)(NN + 1) * 4);
  int* bsums = (int*)alloc(256 * 4);
  int* boffs = (int*)alloc(256 * 4);
  int* srcA = (int*)alloc((size_t)NE * 4);
  int* dstA = (int*)alloc((size_t)NE * 4);
  int* csr = (int*)alloc((size_t)NE * 4);
  float* invd = (float*)alloc((size_t)NN * 4);
  u16* wt = (u16*)alloc((size_t)6 * DD * DD * 2);
  u16* xb = (u16*)alloc((size_t)NN * DD * 2);
  u16* aggb = (u16*)alloc((size_t)NN * DD * 2);

  u16* wt0l = wt + 0 * DD * DD;
  u16* wt0r = wt + 1 * DD * DD;
  u16* wt1l = wt + 2 * DD * DD;
  u16* wt1r = wt + 3 * DD * DD;
  u16* wt2l = wt + 4 * DD * DD;
  u16* wt2r = wt + 5 * DD * DD;

  u16* dob = (u16*)d_out;  // bf16 scratch inside d_out (layer0 y / layer1 x)

  // zero vio/deg/cursor in one memset (contiguous at ws start)
  size_t zbytes = (size_t)((char*)offs - (char*)vio);
  hipMemsetAsync(vio, 0, zbytes, stream);

  k_detect<<<256, 256, 0, stream>>>((const long long*)eidx, vio);
  k_norm<<<512, 256, 0, stream>>>(eidx, vio, srcA, dstA);
  k_count<<<(NE + 255) / 256, 256, 0, stream>>>(dstA, deg);
  k_scan1<<<NB, 256, 0, stream>>>(deg, offs, bsums);
  k_scan2<<<1, 256, 0, stream>>>(bsums, boffs);
  k_scan3<<<NB, 256, 0, stream>>>(offs, boffs, deg, invd);
  k_fill<<<(NE + 255) / 256, 256, 0, stream>>>(srcA, dstA, offs, cursor, csr);

  dim3 wtg(16, 16);
  k_wt<<<wtg, 256, 0, stream>>>(Wl[0], wt0l);
  k_wt<<<wtg, 256, 0, stream>>>(Wr[0], wt0r);
  k_wt<<<wtg, 256, 0, stream>>>(Wl[1], wt1l);
  k_wt<<<wtg, 256, 0, stream>>>(Wr[1], wt1r);
  k_wt<<<wtg, 256, 0, stream>>>(Wl[2], wt2l);
  k_wt<<<wtg, 256, 0, stream>>>(Wr[2], wt2r);

  k_cvt<<<(NN * DD / 8 + 255) / 256, 256, 0, stream>>>(x_in, xb);

  const int GEMM_GRID = 1568;  // 392 rowTiles x 4 colTiles, 8-divisible
  // layer 0: x = xb, y -> d_out (bf16)
  k_agg<<<(NN + 3) / 4, 256, 0, stream>>>(xb, offs, csr, invd, aggb);
  k_gemm<<<GEMM_GRID, 256, 0, stream>>>(aggb, xb, wt0l, wt0r, bl[0], dob, (float*)nullptr, 1);
  // layer 1: x = d_out (bf16), y -> xb
  k_agg<<<(NN + 3) / 4, 256, 0, stream>>>(dob, offs, csr, invd, aggb);
  k_gemm<<<GEMM_GRID, 256, 0, stream>>>(aggb, dob, wt1l, wt1r, bl[1], xb, (float*)nullptr, 1);
  // layer 2: x = xb, y -> d_out (f32, no relu)
  k_agg<<<(NN + 3) / 4, 256, 0, stream>>>(xb, offs, csr, invd, aggb);
  k_gemm<<<GEMM_GRID, 256, 0, stream>>>(aggb, xb, wt2l, wt2r, bl[2], (u16*)nullptr, (float*)d_out, 0);

  (void)in_sizes; (void)n_in; (void)out_size; (void)ws_size;
}

// Round 6
// 516.231 us; speedup vs baseline: 1.0508x; 1.0508x over previous
//
#include <hip/hip_runtime.h>

#define NN 50000
#define NE 400000
#define DD 512
#define NB 196  // ceil(NN/256)

typedef unsigned short u16;
typedef float f32x4 __attribute__((ext_vector_type(4)));
typedef __bf16 bf16x8 __attribute__((ext_vector_type(8)));

__device__ __forceinline__ u16 f2bf(float f) {
  unsigned u = __builtin_bit_cast(unsigned, f);
  unsigned r = (u + 0x7FFFu + ((u >> 16) & 1u)) >> 16;
  return (u16)r;
}
__device__ __forceinline__ float bf_lo(unsigned v) {
  return __builtin_bit_cast(float, v << 16);
}
__device__ __forceinline__ float bf_hi(unsigned v) {
  return __builtin_bit_cast(float, v & 0xffff0000u);
}

__device__ __forceinline__ void gload16(const void* g, void* l) {
  __builtin_amdgcn_global_load_lds(
      (const __attribute__((address_space(1))) unsigned int*)g,
      (__attribute__((address_space(3))) unsigned int*)l, 16, 0, 0);
}

// ---------- edge dtype detect + normalize ----------
__global__ void k_detect(const long long* __restrict__ p, int* __restrict__ vio) {
  bool bad = false;
  for (int i = blockIdx.x * blockDim.x + threadIdx.x; i < NE; i += blockDim.x * gridDim.x) {
    long long v = p[i];
    bad |= (v < 0 || v >= NN);
  }
  unsigned long long m = __ballot(bad);
  if (m != 0ull && (threadIdx.x & 63) == 0) atomicOr(vio, 1);
}

__global__ void k_norm(const void* __restrict__ ep, const int* __restrict__ vio,
                       int* __restrict__ src, int* __restrict__ dst) {
  bool is64 = (*vio == 0);
  for (int e = blockIdx.x * blockDim.x + threadIdx.x; e < NE; e += blockDim.x * gridDim.x) {
    if (is64) {
      const long long* p = (const long long*)ep;
      src[e] = (int)p[e];
      dst[e] = (int)p[NE + e];
    } else {
      const int* p = (const int*)ep;
      src[e] = p[e];
      dst[e] = p[NE + e];
    }
  }
}

// ---------- degree / scan / CSR ----------
__global__ void k_count(const int* __restrict__ dst, int* __restrict__ deg) {
  int e = blockIdx.x * 256 + threadIdx.x;
  if (e < NE) atomicAdd(&deg[dst[e]], 1);
}

__global__ void k_scan1(const int* __restrict__ deg, int* __restrict__ offs,
                        int* __restrict__ bsums) {
  __shared__ int sm[256];
  int t = threadIdx.x, i = blockIdx.x * 256 + t;
  int v = (i < NN) ? deg[i] : 0;
  sm[t] = v;
  __syncthreads();
  int x = v;
  for (int d = 1; d < 256; d <<= 1) {
    int y = (t >= d) ? sm[t - d] : 0;
    __syncthreads();
    x += y;
    sm[t] = x;
    __syncthreads();
  }
  if (i < NN) offs[i + 1] = x;
  if (t == 255) bsums[blockIdx.x] = x;
}

__global__ void k_scan2(const int* __restrict__ bsums, int* __restrict__ boffs) {
  __shared__ int sm[256];
  int t = threadIdx.x;
  int v = (t < NB) ? bsums[t] : 0;
  sm[t] = v;
  __syncthreads();
  int x = v;
  for (int d = 1; d < 256; d <<= 1) {
    int y = (t >= d) ? sm[t - d] : 0;
    __syncthreads();
    x += y;
    sm[t] = x;
    __syncthreads();
  }
  if (t < NB) boffs[t] = x - v;  // exclusive
}

__global__ void k_scan3(int* __restrict__ offs, const int* __restrict__ boffs,
                        const int* __restrict__ deg, float* __restrict__ invd) {
  int i = blockIdx.x * 256 + threadIdx.x;
  if (i == 0) offs[0] = 0;
  if (i < NN) {
    offs[i + 1] += boffs[i >> 8];
    int dg = deg[i];
    if (dg < 1) dg = 1;
    invd[i] = 1.0f / (float)dg;
  }
}

__global__ void k_fill(const int* __restrict__ src, const int* __restrict__ dst,
                       const int* __restrict__ offs, int* __restrict__ cursor,
                       int* __restrict__ csr) {
  int e = blockIdx.x * 256 + threadIdx.x;
  if (e < NE) {
    int d = dst[e];
    int p = atomicAdd(&cursor[d], 1);
    csr[offs[d] + p] = src[e];
  }
}

// ---------- weight transpose + bf16 convert: Wt[n][k] = W[k][n] ----------
__global__ void k_wt(const float* __restrict__ W, u16* __restrict__ Wt) {
  __shared__ float t[32][33];
  int tx = threadIdx.x & 31, ty = threadIdx.x >> 5;  // 32x8
  int bx = blockIdx.x, by = blockIdx.y;
#pragma unroll
  for (int i = 0; i < 32; i += 8)
    t[ty + i][tx] = W[(size_t)(bx * 32 + ty + i) * DD + by * 32 + tx];
  __syncthreads();
#pragma unroll
  for (int i = 0; i < 32; i += 8)
    Wt[(size_t)(by * 32 + ty + i) * DD + bx * 32 + tx] = f2bf(t[tx][ty + i]);
}

// ---------- x f32 -> bf16 ----------
__global__ void k_cvt(const float* __restrict__ x, u16* __restrict__ xb) {
  size_t i = (size_t)(blockIdx.x * 256 + threadIdx.x) * 8;
  float4 a = *(const float4*)(x + i);
  float4 b = *(const float4*)(x + i + 4);
  uint4 o;
  o.x = (unsigned)f2bf(a.x) | ((unsigned)f2bf(a.y) << 16);
  o.y = (unsigned)f2bf(a.z) | ((unsigned)f2bf(a.w) << 16);
  o.z = (unsigned)f2bf(b.x) | ((unsigned)f2bf(b.y) << 16);
  o.w = (unsigned)f2bf(b.z) | ((unsigned)f2bf(b.w) << 16);
  *(uint4*)(xb + i) = o;
}

// ---------- aggregation: one wave per node, 4-deep load pipeline ----------
__global__ __launch_bounds__(256) void k_agg(const u16* __restrict__ xb,
                                             const int* __restrict__ offs,
                                             const int* __restrict__ csr,
                                             const float* __restrict__ invd,
                                             u16* __restrict__ agg) {
  int node = blockIdx.x * 4 + (threadIdx.x >> 6);
  int lane = threadIdx.x & 63;
  if (node >= NN) return;
  int s = offs[node], e = offs[node + 1];
  float a0 = 0, a1 = 0, a2 = 0, a3 = 0, a4 = 0, a5 = 0, a6 = 0, a7 = 0;
  int j = s;
  for (; j + 4 <= e; j += 4) {
    int u0 = csr[j], u1 = csr[j + 1], u2 = csr[j + 2], u3 = csr[j + 3];
    uint4 v0 = *(const uint4*)(xb + (size_t)u0 * DD + lane * 8);
    uint4 v1 = *(const uint4*)(xb + (size_t)u1 * DD + lane * 8);
    uint4 v2 = *(const uint4*)(xb + (size_t)u2 * DD + lane * 8);
    uint4 v3 = *(const uint4*)(xb + (size_t)u3 * DD + lane * 8);
    a0 += bf_lo(v0.x); a1 += bf_hi(v0.x); a2 += bf_lo(v0.y); a3 += bf_hi(v0.y);
    a4 += bf_lo(v0.z); a5 += bf_hi(v0.z); a6 += bf_lo(v0.w); a7 += bf_hi(v0.w);
    a0 += bf_lo(v1.x); a1 += bf_hi(v1.x); a2 += bf_lo(v1.y); a3 += bf_hi(v1.y);
    a4 += bf_lo(v1.z); a5 += bf_hi(v1.z); a6 += bf_lo(v1.w); a7 += bf_hi(v1.w);
    a0 += bf_lo(v2.x); a1 += bf_hi(v2.x); a2 += bf_lo(v2.y); a3 += bf_hi(v2.y);
    a4 += bf_lo(v2.z); a5 += bf_hi(v2.z); a6 += bf_lo(v2.w); a7 += bf_hi(v2.w);
    a0 += bf_lo(v3.x); a1 += bf_hi(v3.x); a2 += bf_lo(v3.y); a3 += bf_hi(v3.y);
    a4 += bf_lo(v3.z); a5 += bf_hi(v3.z); a6 += bf_lo(v3.w); a7 += bf_hi(v3.w);
  }
  for (; j < e; ++j) {
    int u = csr[j];
    uint4 v = *(const uint4*)(xb + (size_t)u * DD + lane * 8);
    a0 += bf_lo(v.x); a1 += bf_hi(v.x); a2 += bf_lo(v.y); a3 += bf_hi(v.y);
    a4 += bf_lo(v.z); a5 += bf_hi(v.z); a6 += bf_lo(v.w); a7 += bf_hi(v.w);
  }
  float sc = invd[node];
  uint4 o;
  o.x = (unsigned)f2bf(a0 * sc) | ((unsigned)f2bf(a1 * sc) << 16);
  o.y = (unsigned)f2bf(a2 * sc) | ((unsigned)f2bf(a3 * sc) << 16);
  o.z = (unsigned)f2bf(a4 * sc) | ((unsigned)f2bf(a5 * sc) << 16);
  o.w = (unsigned)f2bf(a6 * sc) | ((unsigned)f2bf(a7 * sc) << 16);
  *(uint4*)(agg + (size_t)node * DD + lane * 8) = o;
}

// ---------- fused GEMM, m201-style 8-phase 256x256 ----------
// BM=BN=256, BK=64, 8 waves (2M x 4N), wave tile 128x64. LDS 128KB =
// 2 ring-slots x {A: 2 half-tiles, B: 2 half-tiles}, half-tile = 128x64 bf16.
// Per iteration (2 K-tiles): 8 phases {ds-read subtile | stage 1 half-tile |
// barrier | lgkmcnt(0) | setprio(1) 16xMFMA setprio(0) | [vmcnt(4) @ph4,ph8]
// | barrier}. Each half-tile region is overwritten exactly one phase after
// its last reader's closing barrier. XOR granule swizzle (R2/R4: 0 conflicts).
#define RD_A(D, MB)                                                        \
  _Pragma("unroll") for (int m_ = 0; m_ < 4; ++m_)                         \
  _Pragma("unroll") for (int ks_ = 0; ks_ < 2; ++ks_) {                    \
    int r_ = (MB + m_) * 16 + lr;                                          \
    a8[m_ * 2 + ks_] = *(const bf16x8*)(As##D + r_ * 64 +                  \
                        (((ks_ * 4 + hi) ^ (r_ & 7)) << 3));               \
  }
#define RD_B(D, NB, DST)                                                   \
  _Pragma("unroll") for (int n_ = 0; n_ < 2; ++n_)                         \
  _Pragma("unroll") for (int ks_ = 0; ks_ < 2; ++ks_) {                    \
    int r_ = bbase + (NB + n_) * 16 + lr;                                  \
    DST[n_ * 2 + ks_] = *(const bf16x8*)(Bs##D + r_ * 64 +                 \
                        (((ks_ * 4 + hi) ^ (r_ & 7)) << 3));               \
  }
#define MFMA_Q(MB, NB, BV)                                                 \
  __builtin_amdgcn_s_setprio(1);                                           \
  _Pragma("unroll") for (int m_ = 0; m_ < 4; ++m_)                         \
  _Pragma("unroll") for (int n_ = 0; n_ < 2; ++n_)                         \
  _Pragma("unroll") for (int ks_ = 0; ks_ < 2; ++ks_)                      \
    acc[MB + m_][NB + n_] = __builtin_amdgcn_mfma_f32_16x16x32_bf16(       \
        a8[m_ * 2 + ks_], BV[n_ * 2 + ks_], acc[MB + m_][NB + n_], 0, 0, 0); \
  __builtin_amdgcn_s_setprio(0);
#define PH_BAR()                                                           \
  __builtin_amdgcn_s_barrier();                                            \
  asm volatile("s_waitcnt lgkmcnt(0)" ::: "memory");                       \
  __builtin_amdgcn_sched_barrier(0);
#define PH_END() __builtin_amdgcn_s_barrier();
#define PH_END_V4()                                                        \
  asm volatile("s_waitcnt vmcnt(4)" ::: "memory");                         \
  __builtin_amdgcn_s_barrier();
#define PH_END_V0()                                                        \
  asm volatile("s_waitcnt vmcnt(0)" ::: "memory");                         \
  __builtin_amdgcn_s_barrier();

__global__ __launch_bounds__(512, 2) void k_gemm(const u16* __restrict__ Aagg,
                                                 const u16* __restrict__ Ax,
                                                 const u16* __restrict__ Wlt,
                                                 const u16* __restrict__ Wrt,
                                                 const float* __restrict__ bias,
                                                 u16* __restrict__ ybf,
                                                 float* __restrict__ yf,
                                                 int do_relu) {
  // ring-slot d: A halves at d*32768 + half*8192; B at d*32768+16384+half*8192
  __shared__ u16 sh[65536] __attribute__((aligned(16)));

  int tid = threadIdx.x;
  int w = tid >> 6, lane = tid & 63;
  int wr = w >> 2, wc = w & 3;          // 2M x 4N
  int lr = lane & 15;
  int hi = lane >> 4;                   // 0..3
  int srow8 = lane >> 3;                // 0..7
  int gsw = ((lane & 7) ^ srow8) << 3;  // swizzled source granule (elems)
  int bbase = (wc & 1) * 64;            // B local-row base within its half

  // XCD-bijective decode (392 = 8 x 49): consecutive same-XCD blocks share rowT
  int bid = blockIdx.x;
  int lin2 = (bid & 7) * 49 + (bid >> 3);
  int rowT = lin2 >> 1, colT = lin2 & 1;
  int blockRow = rowT * 256;
  int nbase = colT * 256;

  const u16* As0 = sh + wr * 8192;
  const u16* As1 = sh + 32768 + wr * 8192;
  const u16* Bs0 = sh + 16384 + (wc >> 1) * 8192;
  const u16* Bs1 = sh + 49152 + (wc >> 1) * 8192;

  f32x4 acc[8][4];
#pragma unroll
  for (int m = 0; m < 8; ++m)
#pragma unroll
    for (int n = 0; n < 4; ++n) acc[m][n] = (f32x4){0.f, 0.f, 0.f, 0.f};

  // stage one A half-tile (128x64) of K-tile kt into ring-slot d
  auto stageA = [&](int kt, int d, int half) {
    const u16* Ap = (kt < 8) ? Aagg : Ax;
    int kb = (kt & 7) << 6;
    u16* dst = sh + d * 32768 + half * 8192 + w * 1024;
    int r0 = blockRow + half * 128 + w * 16 + srow8;
    int r1 = r0 + 8;
    if (r0 > NN - 1) r0 = NN - 1;
    if (r1 > NN - 1) r1 = NN - 1;
    gload16(Ap + (size_t)r0 * DD + kb + gsw, dst);
    gload16(Ap + (size_t)r1 * DD + kb + gsw, dst + 512);
  };
  auto stageB = [&](int kt, int d, int half) {
    const u16* Bp = (kt < 8) ? Wlt : Wrt;
    int kb = (kt & 7) << 6;
    u16* dst = sh + d * 32768 + 16384 + half * 8192 + w * 1024;
    int r = nbase + half * 128 + w * 16 + srow8;
    gload16(Bp + (size_t)r * DD + kb + gsw, dst);
    gload16(Bp + (size_t)(r + 8) * DD + kb + gsw, dst + 512);
  };

  bf16x8 a8[8], bL[4], bH[4];

  // prologue: slot0 = kt0 (all 4 half-tiles), slot1 = B halves of kt1
  stageA(0, 0, 0); stageA(0, 0, 1); stageB(0, 0, 0); stageB(0, 0, 1);
  stageB(1, 1, 0); stageB(1, 1, 1);
  asm volatile("s_waitcnt vmcnt(4)" ::: "memory");  // kt0 landed; kt1-B in flight
  __builtin_amdgcn_s_barrier();

  for (int i = 0; i < 7; ++i) {
    int k1 = 2 * i + 1;
    // ph1: read slot0 A-lo + B-lo; stage slot1.A0 <- A0(2i+1); Q(lo,lo)
    RD_A(0, 0) RD_B(0, 0, bL) stageA(k1, 1, 0);
    PH_BAR() MFMA_Q(0, 0, bL) PH_END()
    // ph2: read B-hi; stage slot1.A1 <- A1(2i+1); Q(lo,hi)
    RD_B(0, 2, bH) stageA(k1, 1, 1);
    PH_BAR() MFMA_Q(0, 2, bH) PH_END()
    // ph3: read A-hi; stage slot0.B0 <- B0(2i+2); Q(hi,hi)
    RD_A(0, 4) stageB(k1 + 1, 0, 0);
    PH_BAR() MFMA_Q(4, 2, bH) PH_END()
    // ph4: stage slot0.B1 <- B1(2i+2); Q(hi,lo); vmcnt(4)
    stageB(k1 + 1, 0, 1);
    PH_BAR() MFMA_Q(4, 0, bL) PH_END_V4()
    // ph5: read slot1 A-lo + B-lo; stage slot0.A0 <- A0(2i+2); Q(lo,lo)
    RD_A(1, 0) RD_B(1, 0, bL) stageA(k1 + 1, 0, 0);
    PH_BAR() MFMA_Q(0, 0, bL) PH_END()
    // ph6: read B-hi; stage slot0.A1 <- A1(2i+2); Q(lo,hi)
    RD_B(1, 2, bH) stageA(k1 + 1, 0, 1);
    PH_BAR() MFMA_Q(0, 2, bH) PH_END()
    // ph7: read A-hi; stage slot1.B0 <- B0(2i+3); Q(hi,hi)
    RD_A(1, 4) stageB(k1 + 2, 1, 0);
    PH_BAR() MFMA_Q(4, 2, bH) PH_END()
    // ph8: stage slot1.B1 <- B1(2i+3); Q(hi,lo); vmcnt(4)
    stageB(k1 + 2, 1, 1);
    PH_BAR() MFMA_Q(4, 0, bL) PH_END_V4()
  }
  // peeled iter 7 (kt 14,15): only A(15) left to stage
  RD_A(0, 0) RD_B(0, 0, bL) stageA(15, 1, 0);
  PH_BAR() MFMA_Q(0, 0, bL) PH_END()
  RD_B(0, 2, bH) stageA(15, 1, 1);
  PH_BAR() MFMA_Q(0, 2, bH) PH_END()
  RD_A(0, 4)
  PH_BAR() MFMA_Q(4, 2, bH) PH_END()
  PH_BAR() MFMA_Q(4, 0, bL) PH_END_V0()
  RD_A(1, 0) RD_B(1, 0, bL)
  PH_BAR() MFMA_Q(0, 0, bL) PH_END()
  RD_B(1, 2, bH)
  PH_BAR() MFMA_Q(0, 2, bH) PH_END()
  RD_A(1, 4)
  PH_BAR() MFMA_Q(4, 2, bH) PH_END()
  PH_BAR() MFMA_Q(4, 0, bL) PH_END()

  if (yf) {
    // f32 output (final layer): direct stores
#pragma unroll
    for (int n = 0; n < 4; ++n) {
      int col = nbase + wc * 64 + n * 16 + lr;
      float bv = bias[col];
#pragma unroll
      for (int m = 0; m < 8; ++m) {
        f32x4 v = acc[m][n];
#pragma unroll
        for (int r = 0; r < 4; ++r) {
          int row = blockRow + wr * 128 + m * 16 + hi * 4 + r;
          if (row < NN) {
            float y = v[r] + bv;
            if (do_relu) y = fmaxf(y, 0.f);
            yf[(size_t)row * DD + col] = y;
          }
        }
      }
    }
  } else {
    // bf16 output: stage 256x256 C tile in sh (128KB) then coalesced writes
    __syncthreads();
#pragma unroll
    for (int n = 0; n < 4; ++n) {
      int col = nbase + wc * 64 + n * 16 + lr;
      float bv = bias[col];
      int g = wc * 8 + n * 2 + (lr >> 3);  // col granule 0..31
#pragma unroll
      for (int m = 0; m < 8; ++m) {
        f32x4 v = acc[m][n];
#pragma unroll
        for (int r = 0; r < 4; ++r) {
          int rl = wr * 128 + m * 16 + hi * 4 + r;
          float y = v[r] + bv;
          if (do_relu) y = fmaxf(y, 0.f);
          sh[rl * 256 + ((g ^ (rl & 31)) << 3) + (lr & 7)] = f2bf(y);
        }
      }
    }
    __syncthreads();
#pragma unroll
    for (int p = 0; p < 16; ++p) {
      int rl = p * 16 + (tid >> 5);
      int gg = tid & 31;
      int grow = blockRow + rl;
      if (grow < NN) {
        uint4 vv = *(const uint4*)(sh + rl * 256 + ((gg ^ (rl & 31)) << 3));
        *(uint4*)(ybf + (size_t)grow * DD + nbase + gg * 8) = vv;
      }
    }
  }
}

extern "C" void kernel_launch(void* const* d_in, const int* in_sizes, int n_in,
                              void* d_out, int out_size, void* d_ws, size_t ws_size,
                              hipStream_t stream) {
  const float* x_in = (const float*)d_in[0];
  const void* eidx = d_in[1];
  const float* Wl[3] = {(const float*)d_in[2], (const float*)d_in[5], (const float*)d_in[8]};
  const float* bl[3] = {(const float*)d_in[3], (const float*)d_in[6], (const float*)d_in[9]};
  const float* Wr[3] = {(const float*)d_in[4], (const float*)d_in[7], (const float*)d_in[10]};

  // workspace layout
  char* w = (char*)d_ws;
  auto alloc = [&](size_t bytes) {
    char* p = w;
    w += (bytes + 255) & ~(size_t)255;
    return p;
  };
  int* vio = (int*)alloc(4);
  int* deg = (int*)alloc((size_t)NN * 4);
  int* cursor = (int*)alloc((size_t)NN * 4);
  int* offs = (int*)alloc((size_t)(NN + 1) * 4);
  int* bsums = (int*)alloc(256 * 4);
  int* boffs = (int*)alloc(256 * 4);
  int* srcA = (int*)alloc((size_t)NE * 4);
  int* dstA = (int*)alloc((size_t)NE * 4);
  int* csr = (int*)alloc((size_t)NE * 4);
  float* invd = (float*)alloc((size_t)NN * 4);
  u16* wt = (u16*)alloc((size_t)6 * DD * DD * 2);
  u16* xb = (u16*)alloc((size_t)NN * DD * 2);
  u16* aggb = (u16*)alloc((size_t)NN * DD * 2);

  u16* wt0l = wt + 0 * DD * DD;
  u16* wt0r = wt + 1 * DD * DD;
  u16* wt1l = wt + 2 * DD * DD;
  u16* wt1r = wt + 3 * DD * DD;
  u16* wt2l = wt + 4 * DD * DD;
  u16* wt2r = wt + 5 * DD * DD;

  u16* dob = (u16*)d_out;  // bf16 scratch inside d_out (layer0 y / layer1 x)

  // zero vio/deg/cursor in one memset (contiguous at ws start)
  size_t zbytes = (size_t)((char*)offs - (char*)vio);
  hipMemsetAsync(vio, 0, zbytes, stream);

  k_detect<<<256, 256, 0, stream>>>((const long long*)eidx, vio);
  k_norm<<<512, 256, 0, stream>>>(eidx, vio, srcA, dstA);
  k_count<<<(NE + 255) / 256, 256, 0, stream>>>(dstA, deg);
  k_scan1<<<NB, 256, 0, stream>>>(deg, offs, bsums);
  k_scan2<<<1, 256, 0, stream>>>(bsums, boffs);
  k_scan3<<<NB, 256, 0, stream>>>(offs, boffs, deg, invd);
  k_fill<<<(NE + 255) / 256, 256, 0, stream>>>(srcA, dstA, offs, cursor, csr);

  dim3 wtg(16, 16);
  k_wt<<<wtg, 256, 0, stream>>>(Wl[0], wt0l);
  k_wt<<<wtg, 256, 0, stream>>>(Wr[0], wt0r);
  k_wt<<<wtg, 256, 0, stream>>>(Wl[1], wt1l);
  k_wt<<<wtg, 256, 0, stream>>>(Wr[1], wt1r);
  k_wt<<<wtg, 256, 0, stream>>>(Wl[2], wt2l);
  k_wt<<<wtg, 256, 0, stream>>>(Wr[2], wt2r);

  k_cvt<<<(NN * DD / 8 + 255) / 256, 256, 0, stream>>>(x_in, xb);

  const int GEMM_GRID = 392;  // 196 rowTiles x 2 colTiles = 8 x 49
  // layer 0: x = xb, y -> d_out (bf16)
  k_agg<<<(NN + 3) / 4, 256, 0, stream>>>(xb, offs, csr, invd, aggb);
  k_gemm<<<GEMM_GRID, 512, 0, stream>>>(aggb, xb, wt0l, wt0r, bl[0], dob, (float*)nullptr, 1);
  // layer 1: x = d_out (bf16), y -> xb
  k_agg<<<(NN + 3) / 4, 256, 0, stream>>>(dob, offs, csr, invd, aggb);
  k_gemm<<<GEMM_GRID, 512, 0, stream>>>(aggb, dob, wt1l, wt1r, bl[1], xb, (float*)nullptr, 1);
  // layer 2: x = xb, y -> d_out (f32, no relu)
  k_agg<<<(NN + 3) / 4, 256, 0, stream>>>(xb, offs, csr, invd, aggb);
  k_gemm<<<GEMM_GRID, 512, 0, stream>>>(aggb, xb, wt2l, wt2r, bl[2], (u16*)nullptr, (float*)d_out, 0);

  (void)in_sizes; (void)n_in; (void)out_size; (void)ws_size;
}

// Round 7
// 482.806 us; speedup vs baseline: 1.1236x; 1.0692x over previous
//
#include <hip/hip_runtime.h>

#define NN 50000
#define NE 400000
#define DD 512
#define NB 196  // ceil(NN/256)

typedef unsigned short u16;
typedef float f32x4 __attribute__((ext_vector_type(4)));
typedef __bf16 bf16x8 __attribute__((ext_vector_type(8)));

__device__ __forceinline__ u16 f2bf(float f) {
  unsigned u = __builtin_bit_cast(unsigned, f);
  unsigned r = (u + 0x7FFFu + ((u >> 16) & 1u)) >> 16;
  return (u16)r;
}
__device__ __forceinline__ float bf_lo(unsigned v) {
  return __builtin_bit_cast(float, v << 16);
}
__device__ __forceinline__ float bf_hi(unsigned v) {
  return __builtin_bit_cast(float, v & 0xffff0000u);
}

__device__ __forceinline__ void gload16(const void* g, void* l) {
  __builtin_amdgcn_global_load_lds(
      (const __attribute__((address_space(1))) unsigned int*)g,
      (__attribute__((address_space(3))) unsigned int*)l, 16, 0, 0);
}

// ---------- edge dtype detect ----------
__global__ void k_detect(const long long* __restrict__ p, int* __restrict__ vio) {
  bool bad = false;
  for (int i = blockIdx.x * blockDim.x + threadIdx.x; i < NE; i += blockDim.x * gridDim.x) {
    long long v = p[i];
    bad |= (v < 0 || v >= NN);
  }
  unsigned long long m = __ballot(bad);
  if (m != 0ull && (threadIdx.x & 63) == 0) atomicOr(vio, 1);
}

// ---------- normalize edges + degree count (fused) ----------
__global__ void k_normcnt(const void* __restrict__ ep, const int* __restrict__ vio,
                          int* __restrict__ src, int* __restrict__ dst,
                          int* __restrict__ deg) {
  bool is64 = (*vio == 0);
  for (int e = blockIdx.x * blockDim.x + threadIdx.x; e < NE; e += blockDim.x * gridDim.x) {
    int s_, d_;
    if (is64) {
      const long long* p = (const long long*)ep;
      s_ = (int)p[e];
      d_ = (int)p[NE + e];
    } else {
      const int* p = (const int*)ep;
      s_ = p[e];
      d_ = p[NE + e];
    }
    src[e] = s_;
    dst[e] = d_;
    atomicAdd(&deg[d_], 1);
  }
}

// ---------- scan / CSR ----------
__global__ void k_scan1(const int* __restrict__ deg, int* __restrict__ offs,
                        int* __restrict__ bsums) {
  __shared__ int sm[256];
  int t = threadIdx.x, i = blockIdx.x * 256 + t;
  int v = (i < NN) ? deg[i] : 0;
  sm[t] = v;
  __syncthreads();
  int x = v;
  for (int d = 1; d < 256; d <<= 1) {
    int y = (t >= d) ? sm[t - d] : 0;
    __syncthreads();
    x += y;
    sm[t] = x;
    __syncthreads();
  }
  if (i < NN) offs[i + 1] = x;
  if (t == 255) bsums[blockIdx.x] = x;
}

__global__ void k_scan2(const int* __restrict__ bsums, int* __restrict__ boffs) {
  __shared__ int sm[256];
  int t = threadIdx.x;
  int v = (t < NB) ? bsums[t] : 0;
  sm[t] = v;
  __syncthreads();
  int x = v;
  for (int d = 1; d < 256; d <<= 1) {
    int y = (t >= d) ? sm[t - d] : 0;
    __syncthreads();
    x += y;
    sm[t] = x;
    __syncthreads();
  }
  if (t < NB) boffs[t] = x - v;  // exclusive
}

__global__ void k_scan3(int* __restrict__ offs, const int* __restrict__ boffs,
                        const int* __restrict__ deg, float* __restrict__ invd) {
  int i = blockIdx.x * 256 + threadIdx.x;
  if (i == 0) offs[0] = 0;
  if (i < NN) {
    offs[i + 1] += boffs[i >> 8];
    int dg = deg[i];
    if (dg < 1) dg = 1;
    invd[i] = 1.0f / (float)dg;
  }
}

__global__ void k_fill(const int* __restrict__ src, const int* __restrict__ dst,
                       const int* __restrict__ offs, int* __restrict__ cursor,
                       int* __restrict__ csr) {
  int e = blockIdx.x * 256 + threadIdx.x;
  if (e < NE) {
    int d = dst[e];
    int p = atomicAdd(&cursor[d], 1);
    csr[offs[d] + p] = src[e];
  }
}

// ---------- all-6 weight transpose + bf16 convert (one dispatch) ----------
__global__ void k_wt6(const float* __restrict__ W0, const float* __restrict__ W1,
                      const float* __restrict__ W2, const float* __restrict__ W3,
                      const float* __restrict__ W4, const float* __restrict__ W5,
                      u16* __restrict__ wt) {
  __shared__ float t[32][33];
  const float* W;
  switch (blockIdx.z) {
    case 0: W = W0; break;
    case 1: W = W1; break;
    case 2: W = W2; break;
    case 3: W = W3; break;
    case 4: W = W4; break;
    default: W = W5; break;
  }
  u16* Wt = wt + (size_t)blockIdx.z * DD * DD;
  int tx = threadIdx.x & 31, ty = threadIdx.x >> 5;  // 32x8
  int bx = blockIdx.x, by = blockIdx.y;
#pragma unroll
  for (int i = 0; i < 32; i += 8)
    t[ty + i][tx] = W[(size_t)(bx * 32 + ty + i) * DD + by * 32 + tx];
  __syncthreads();
#pragma unroll
  for (int i = 0; i < 32; i += 8)
    Wt[(size_t)(by * 32 + ty + i) * DD + bx * 32 + tx] = f2bf(t[tx][ty + i]);
}

// ---------- x f32 -> bf16 ----------
__global__ void k_cvt(const float* __restrict__ x, u16* __restrict__ xb) {
  size_t i = (size_t)(blockIdx.x * 256 + threadIdx.x) * 8;
  float4 a = *(const float4*)(x + i);
  float4 b = *(const float4*)(x + i + 4);
  uint4 o;
  o.x = (unsigned)f2bf(a.x) | ((unsigned)f2bf(a.y) << 16);
  o.y = (unsigned)f2bf(a.z) | ((unsigned)f2bf(a.w) << 16);
  o.z = (unsigned)f2bf(b.x) | ((unsigned)f2bf(b.y) << 16);
  o.w = (unsigned)f2bf(b.z) | ((unsigned)f2bf(b.w) << 16);
  *(uint4*)(xb + i) = o;
}

#define ACC8(V)                                                     \
  a0 += bf_lo(V.x); a1 += bf_hi(V.x); a2 += bf_lo(V.y); a3 += bf_hi(V.y); \
  a4 += bf_lo(V.z); a5 += bf_hi(V.z); a6 += bf_lo(V.w); a7 += bf_hi(V.w);

// ---------- aggregation: one wave per node, 8-deep load pipeline ----------
// deg mean = 8: one batch of 8 in-flight row loads covers the typical node
// with a single cache-latency exposure (was 2 exposures at 4-deep).
__global__ __launch_bounds__(256) void k_agg(const u16* __restrict__ xb,
                                             const int* __restrict__ offs,
                                             const int* __restrict__ csr,
                                             const float* __restrict__ invd,
                                             u16* __restrict__ agg) {
  int node = blockIdx.x * 4 + (threadIdx.x >> 6);
  int lane = threadIdx.x & 63;
  if (node >= NN) return;
  int s = offs[node], e = offs[node + 1];
  float a0 = 0, a1 = 0, a2 = 0, a3 = 0, a4 = 0, a5 = 0, a6 = 0, a7 = 0;
  int j = s;
  for (; j + 8 <= e; j += 8) {
    int u0 = csr[j], u1 = csr[j + 1], u2 = csr[j + 2], u3 = csr[j + 3];
    int u4 = csr[j + 4], u5 = csr[j + 5], u6 = csr[j + 6], u7 = csr[j + 7];
    uint4 v0 = *(const uint4*)(xb + (size_t)u0 * DD + lane * 8);
    uint4 v1 = *(const uint4*)(xb + (size_t)u1 * DD + lane * 8);
    uint4 v2 = *(const uint4*)(xb + (size_t)u2 * DD + lane * 8);
    uint4 v3 = *(const uint4*)(xb + (size_t)u3 * DD + lane * 8);
    uint4 v4 = *(const uint4*)(xb + (size_t)u4 * DD + lane * 8);
    uint4 v5 = *(const uint4*)(xb + (size_t)u5 * DD + lane * 8);
    uint4 v6 = *(const uint4*)(xb + (size_t)u6 * DD + lane * 8);
    uint4 v7 = *(const uint4*)(xb + (size_t)u7 * DD + lane * 8);
    ACC8(v0) ACC8(v1) ACC8(v2) ACC8(v3) ACC8(v4) ACC8(v5) ACC8(v6) ACC8(v7)
  }
  for (; j + 4 <= e; j += 4) {
    int u0 = csr[j], u1 = csr[j + 1], u2 = csr[j + 2], u3 = csr[j + 3];
    uint4 v0 = *(const uint4*)(xb + (size_t)u0 * DD + lane * 8);
    uint4 v1 = *(const uint4*)(xb + (size_t)u1 * DD + lane * 8);
    uint4 v2 = *(const uint4*)(xb + (size_t)u2 * DD + lane * 8);
    uint4 v3 = *(const uint4*)(xb + (size_t)u3 * DD + lane * 8);
    ACC8(v0) ACC8(v1) ACC8(v2) ACC8(v3)
  }
  for (; j < e; ++j) {
    int u = csr[j];
    uint4 v = *(const uint4*)(xb + (size_t)u * DD + lane * 8);
    ACC8(v)
  }
  float sc = invd[node];
  uint4 o;
  o.x = (unsigned)f2bf(a0 * sc) | ((unsigned)f2bf(a1 * sc) << 16);
  o.y = (unsigned)f2bf(a2 * sc) | ((unsigned)f2bf(a3 * sc) << 16);
  o.z = (unsigned)f2bf(a4 * sc) | ((unsigned)f2bf(a5 * sc) << 16);
  o.w = (unsigned)f2bf(a6 * sc) | ((unsigned)f2bf(a7 * sc) << 16);
  *(uint4*)(agg + (size_t)node * DD + lane * 8) = o;
}

// ---------- fused GEMM: C = relu?(Agg@Wl + X@Wr + b) ----------
// R4 structure (best measured: 90us): BM=128, BN=128, BK=64, 4 waves (2x2),
// 2-deep counted-vmcnt pipeline: prologue stages tiles 0,1; each iter waits
// vmcnt(8), raw s_barrier, compute, raw s_barrier, stage(t+2). vmcnt never
// drains to 0 in the main loop. XOR-swizzled LDS (0 conflicts), XCD-bijective
// grid swizzle, setprio around MFMAs, LDS-staged coalesced bf16 epilogue.
__global__ __launch_bounds__(256) void k_gemm(const u16* __restrict__ Aagg,
                                              const u16* __restrict__ Ax,
                                              const u16* __restrict__ Wlt,
                                              const u16* __restrict__ Wrt,
                                              const float* __restrict__ bias,
                                              u16* __restrict__ ybf,
                                              float* __restrict__ yf,
                                              int do_relu) {
  // A0 [0,8192) A1 [8192,16384) B0 [16384,24576) B1 [24576,32768)  (u16 idx)
  __shared__ u16 sh[32768] __attribute__((aligned(16)));

  int tid = threadIdx.x;
  int w = tid >> 6, lane = tid & 63;
  int wr = w >> 1, wc = w & 1;
  int lr = lane & 15;
  int hi = lane >> 4;  // 0..3

  // XCD-bijective decode: same rowTile's 4 colTiles land consecutively on one XCD
  int lin = blockIdx.x;
  int xcd = lin & 7;
  int t = lin >> 3;
  int colT = t & 3;
  int rowT = (t >> 2) * 8 + xcd;  // 0..391
  int blockRow = rowT * 128;
  int nbase = colT * 128;

  // staging source pre-swizzle: LDS granule (row, posg) holds global granule posg^(row&7)
  int srow = lane >> 3;                 // row-within-segment 0..7 (== destRow&7)
  int scol = ((lane & 7) ^ srow) << 3;  // swizzled source column (elements)

  f32x4 acc[4][4];
#pragma unroll
  for (int m = 0; m < 4; ++m)
#pragma unroll
    for (int n = 0; n < 4; ++n) acc[m][n] = (f32x4){0.f, 0.f, 0.f, 0.f};

  // stage K-tile kt (0..15) into buffer b: 8 gload16 per thread
  auto stage = [&](int kt, int b) {
    const u16* Ap = (kt < 8) ? Aagg : Ax;
    const u16* Bp = (kt < 8) ? Wlt : Wrt;
    int kb = (kt & 7) << 6;
    u16* Ad = sh + b * 8192;
    u16* Bd = sh + 16384 + b * 8192;
#pragma unroll
    for (int i = 0; i < 4; ++i) {
      int s = (w << 2) + i;
      int ar = blockRow + s * 8 + srow;
      if (ar > NN - 1) ar = NN - 1;
      int br = nbase + s * 8 + srow;
      gload16(Ap + (size_t)ar * DD + kb + scol, Ad + s * 512);
      gload16(Bp + (size_t)br * DD + kb + scol, Bd + s * 512);
    }
  };

  auto compute = [&](int cur) {
    const u16* As = sh + cur * 8192;
    const u16* Bs = sh + 16384 + cur * 8192;
#pragma unroll
    for (int k2 = 0; k2 < 2; ++k2) {
      int gA = (k2 << 2) + hi;  // wanted k-granule 0..7
      bf16x8 af[4], bfr[4];
#pragma unroll
      for (int m = 0; m < 4; ++m) {
        int r = wr * 64 + m * 16 + lr;
        af[m] = *(const bf16x8*)(As + r * 64 + ((gA ^ (r & 7)) << 3));
      }
#pragma unroll
      for (int n = 0; n < 4; ++n) {
        int r = wc * 64 + n * 16 + lr;
        bfr[n] = *(const bf16x8*)(Bs + r * 64 + ((gA ^ (r & 7)) << 3));
      }
      __builtin_amdgcn_s_setprio(1);
#pragma unroll
      for (int m = 0; m < 4; ++m)
#pragma unroll
        for (int n = 0; n < 4; ++n)
          acc[m][n] = __builtin_amdgcn_mfma_f32_16x16x32_bf16(af[m], bfr[n], acc[m][n], 0, 0, 0);
      __builtin_amdgcn_s_setprio(0);
    }
  };

  stage(0, 0);
  stage(1, 1);  // 16 loads outstanding

  for (int kt = 0; kt < 15; ++kt) {
    int cur = kt & 1;
    // tile kt's 8 loads done; tile kt+1's 8 remain in flight
    asm volatile("s_waitcnt vmcnt(8)" ::: "memory");
    __builtin_amdgcn_s_barrier();
    compute(cur);
    __builtin_amdgcn_s_barrier();  // all waves done reading buf cur
    if (kt + 2 < 16) stage(kt + 2, cur);
  }
  // last tile: only its own 8 loads outstanding -> full drain
  asm volatile("s_waitcnt vmcnt(0)" ::: "memory");
  __builtin_amdgcn_s_barrier();
  compute(1);
  __builtin_amdgcn_s_barrier();

  if (yf) {
    // f32 output (final layer): direct stores
#pragma unroll
    for (int n = 0; n < 4; ++n) {
      int col = nbase + wc * 64 + n * 16 + lr;
      float bv = bias[col];
#pragma unroll
      for (int m = 0; m < 4; ++m) {
        f32x4 v = acc[m][n];
#pragma unroll
        for (int r = 0; r < 4; ++r) {
          int row = blockRow + wr * 64 + m * 16 + hi * 4 + r;
          if (row < NN) {
            float y = v[r] + bv;
            if (do_relu) y = fmaxf(y, 0.f);
            yf[(size_t)row * DD + col] = y;
          }
        }
      }
    }
  } else {
    // bf16 output: stage C tile (128x128 u16 = 32KB in sh[0..16384)) then coalesced writes
#pragma unroll
    for (int n = 0; n < 4; ++n) {
      int col = nbase + wc * 64 + n * 16 + lr;
      float bv = bias[col];
      int g = wc * 8 + n * 2 + (lr >> 3);  // col granule 0..15
#pragma unroll
      for (int m = 0; m < 4; ++m) {
        f32x4 v = acc[m][n];
#pragma unroll
        for (int r = 0; r < 4; ++r) {
          int rl = wr * 64 + m * 16 + hi * 4 + r;
          float y = v[r] + bv;
          if (do_relu) y = fmaxf(y, 0.f);
          sh[rl * 128 + ((g ^ (rl & 15)) << 3) + (lr & 7)] = f2bf(y);
        }
      }
    }
    __syncthreads();
#pragma unroll
    for (int p = 0; p < 8; ++p) {
      int rl = p * 16 + (tid >> 4);
      int gg = tid & 15;
      int grow = blockRow + rl;
      if (grow < NN) {
        uint4 vv = *(const uint4*)(sh + rl * 128 + ((gg ^ (rl & 15)) << 3));
        *(uint4*)(ybf + (size_t)grow * DD + nbase + gg * 8) = vv;
      }
    }
  }
}

extern "C" void kernel_launch(void* const* d_in, const int* in_sizes, int n_in,
                              void* d_out, int out_size, void* d_ws, size_t ws_size,
                              hipStream_t stream) {
  const float* x_in = (const float*)d_in[0];
  const void* eidx = d_in[1];
  const float* Wl[3] = {(const float*)d_in[2], (const float*)d_in[5], (const float*)d_in[8]};
  const float* bl[3] = {(const float*)d_in[3], (const float*)d_in[6], (const float*)d_in[9]};
  const float* Wr[3] = {(const float*)d_in[4], (const float*)d_in[7], (const float*)d_in[10]};

  // workspace layout
  char* w = (char*)d_ws;
  auto alloc = [&](size_t bytes) {
    char* p = w;
    w += (bytes + 255) & ~(size_t)255;
    return p;
  };
  int* vio = (int*)alloc(4);
  int* deg = (int*)alloc((size_t)NN * 4);
  int* cursor = (int*)alloc((size_t)NN * 4);
  int* offs = (int*)alloc((size_t)(NN + 1) * 4);
  int* bsums = (int*)alloc(256 * 4);
  int* boffs = (int*)alloc(256 * 4);
  int* srcA = (int*)alloc((size_t)NE * 4);
  int* dstA = (int*)alloc((size_t)NE * 4);
  int* csr = (int*)alloc((size_t)NE * 4);
  float* invd = (float*)alloc((size_t)NN * 4);
  u16* wt = (u16*)alloc((size_t)6 * DD * DD * 2);
  u16* xb = (u16*)alloc((size_t)NN * DD * 2);
  u16* aggb = (u16*)alloc((size_t)NN * DD * 2);

  u16* wt0l = wt + 0 * DD * DD;
  u16* wt0r = wt + 1 * DD * DD;
  u16* wt1l = wt + 2 * DD * DD;
  u16* wt1r = wt + 3 * DD * DD;
  u16* wt2l = wt + 4 * DD * DD;
  u16* wt2r = wt + 5 * DD * DD;

  u16* dob = (u16*)d_out;  // bf16 scratch inside d_out (layer0 y / layer1 x)

  // zero vio/deg/cursor in one memset (contiguous at ws start)
  size_t zbytes = (size_t)((char*)offs - (char*)vio);
  hipMemsetAsync(vio, 0, zbytes, stream);

  k_detect<<<256, 256, 0, stream>>>((const long long*)eidx, vio);
  k_normcnt<<<512, 256, 0, stream>>>(eidx, vio, srcA, dstA, deg);
  k_scan1<<<NB, 256, 0, stream>>>(deg, offs, bsums);
  k_scan2<<<1, 256, 0, stream>>>(bsums, boffs);
  k_scan3<<<NB, 256, 0, stream>>>(offs, boffs, deg, invd);
  k_fill<<<(NE + 255) / 256, 256, 0, stream>>>(srcA, dstA, offs, cursor, csr);

  k_wt6<<<dim3(16, 16, 6), 256, 0, stream>>>(Wl[0], Wr[0], Wl[1], Wr[1], Wl[2], Wr[2], wt);
  k_cvt<<<(NN * DD / 8 + 255) / 256, 256, 0, stream>>>(x_in, xb);

  const int GEMM_GRID = 1568;  // 392 rowTiles x 4 colTiles, 8-divisible
  // layer 0: x = xb, y -> d_out (bf16)
  k_agg<<<(NN + 3) / 4, 256, 0, stream>>>(xb, offs, csr, invd, aggb);
  k_gemm<<<GEMM_GRID, 256, 0, stream>>>(aggb, xb, wt0l, wt0r, bl[0], dob, (float*)nullptr, 1);
  // layer 1: x = d_out (bf16), y -> xb
  k_agg<<<(NN + 3) / 4, 256, 0, stream>>>(dob, offs, csr, invd, aggb);
  k_gemm<<<GEMM_GRID, 256, 0, stream>>>(aggb, dob, wt1l, wt1r, bl[1], xb, (float*)nullptr, 1);
  // layer 2: x = xb, y -> d_out (f32, no relu)
  k_agg<<<(NN + 3) / 4, 256, 0, stream>>>(xb, offs, csr, invd, aggb);
  k_gemm<<<GEMM_GRID, 256, 0, stream>>>(aggb, xb, wt2l, wt2r, bl[2], (u16*)nullptr, (float*)d_out, 0);

  (void)in_sizes; (void)n_in; (void)out_size; (void)ws_size;
}